// Round 1
// baseline (1103.744 us; speedup 1.0000x reference)
//
#include <hip/hip_runtime.h>
#include <math.h>

#define CIN 256
#define COUT 256
#define CG 128   // channels per deformable group

// ---------------------------------------------------------------------------
// prep: wT[(g*9+k)*128 + c][oc] = w[oc][g*128+c][k]; scale/shift for fused BN
// ---------------------------------------------------------------------------
__global__ __launch_bounds__(256) void prep_kernel(
    const float* __restrict__ w, const float* __restrict__ bconv,
    const float* __restrict__ gamma, const float* __restrict__ beta,
    const float* __restrict__ mean, const float* __restrict__ var,
    float* __restrict__ wT, float* __restrict__ sc, float* __restrict__ sh) {
  int i = blockIdx.x * 256 + threadIdx.x;   // grid covers 18*128*256 exactly
  int oc = i & 255;
  int c  = (i >> 8) & 127;
  int gk = i >> 15;                          // 0..17
  int g = gk / 9, k = gk % 9;
  wT[i] = w[((size_t)oc * CIN + g * CG + c) * 9 + k];
  if (i < COUT) {
    float s = gamma[i] * rsqrtf(var[i] + 1e-5f);
    sc[i] = s;
    sh[i] = (bconv[i] - mean[i]) * s + beta[i];
  }
}

// ---------------------------------------------------------------------------
// offset/mask conv: 3x3 SAME, 256 -> 54 channels. One block per (b, row).
// 256 threads = 64 px * 4 oc-groups (14 oc each, last group 12).
// ---------------------------------------------------------------------------
__global__ __launch_bounds__(256) void offconv_kernel(
    const float* __restrict__ x, const float* __restrict__ w_off,
    const float* __restrict__ b_off, float* __restrict__ om) {
  __shared__ float xs[16 * 3 * 66];        // 16 ci x 3 rows x (64+2) cols
  __shared__ float wsl[16 * 54 * 12];      // 16 ci x 54 oc x 9 taps (pad 12 for b128)
  int t = threadIdx.x;
  int px = t & 63, ocg = t >> 6;
  int b = blockIdx.x >> 6, y = blockIdx.x & 63;
  int base = ocg * 14;
  int noc = min(14, 54 - base);
  float acc[14];
  #pragma unroll
  for (int j = 0; j < 14; ++j) acc[j] = 0.f;

  for (int cc = 0; cc < 16; ++cc) {        // 16 chunks of 16 input channels
    __syncthreads();                        // protect prior-iter LDS reads
    for (int i = t; i < 16 * 3 * 66; i += 256) {
      int ci = i / 198, r = i % 198;
      int dy = r / 66, col = r % 66;
      int y2 = y + dy - 1, x2 = col - 1;
      float v = 0.f;
      if (y2 >= 0 && y2 < 64 && x2 >= 0 && x2 < 64)
        v = x[(((size_t)b * CIN + cc * 16 + ci) * 64 + y2) * 64 + x2];
      xs[i] = v;
    }
    for (int i = t; i < 16 * 54 * 9; i += 256) {
      int ci = i / 486, r = i % 486;
      int oc = r / 9, k = r % 9;
      wsl[ci * 648 + oc * 12 + k] = w_off[((size_t)oc * CIN + cc * 16 + ci) * 9 + k];
    }
    __syncthreads();
    for (int ci = 0; ci < 16; ++ci) {
      float xv[9];
      #pragma unroll
      for (int dy = 0; dy < 3; ++dy) {
        xv[dy * 3 + 0] = xs[ci * 198 + dy * 66 + px + 0];
        xv[dy * 3 + 1] = xs[ci * 198 + dy * 66 + px + 1];
        xv[dy * 3 + 2] = xs[ci * 198 + dy * 66 + px + 2];
      }
      #pragma unroll
      for (int j = 0; j < 14; ++j) {
        if (j < noc) {
          const float* wp = &wsl[ci * 648 + (base + j) * 12];
          float4 wa = *(const float4*)wp;
          float4 wb = *(const float4*)(wp + 4);
          float w8 = wp[8];
          acc[j] += wa.x * xv[0] + wa.y * xv[1] + wa.z * xv[2] + wa.w * xv[3]
                  + wb.x * xv[4] + wb.y * xv[5] + wb.z * xv[6] + wb.w * xv[7]
                  + w8 * xv[8];
        }
      }
    }
  }
  for (int j = 0; j < noc; ++j) {
    int oc = base + j;
    om[(((size_t)b * 54 + oc) * 64 + y) * 64 + px] = acc[j] + b_off[oc];
  }
}

// ---------------------------------------------------------------------------
// main deformable conv + BN + ReLU. One block per (b, row).
// 256 threads = 64 px * 4 oc-groups; each thread accumulates 64 oc.
// ---------------------------------------------------------------------------
__global__ __launch_bounds__(256) void dconv_kernel(
    const float* __restrict__ x, const float* __restrict__ om,
    const float* __restrict__ wT, const float* __restrict__ sc,
    const float* __restrict__ sh, float* __restrict__ out) {
  __shared__ float vsm[128 * 64];          // sampled values [c within group][px]
  __shared__ float wt[32 * 256];           // staged wT chunk [c][oc]
  __shared__ float swgt[64 * 4];           // bilinear corner weights (x mask)
  __shared__ int   slin[64 * 4];           // clamped corner linear indices
  int t = threadIdx.x;
  int px = t & 63, ocg = t >> 6;
  int b = blockIdx.x >> 6, y = blockIdx.x & 63;
  float acc[64];
  #pragma unroll
  for (int j = 0; j < 64; ++j) acc[j] = 0.f;

  for (int g = 0; g < 2; ++g) {
    for (int k = 0; k < 9; ++k) {
      __syncthreads();                     // protect swgt/vsm from prior iter
      if (t < 64) {
        int chy = g * 9 + k;
        size_t obase = (size_t)b * 54 * 4096 + (size_t)y * 64 + t;
        float oy = om[obase + (size_t)chy * 4096];
        float ox = om[obase + (size_t)(18 + chy) * 4096];
        float mz = om[obase + (size_t)(36 + chy) * 4096];
        float mv = 1.f / (1.f + expf(-mz));
        float py  = (float)(y + (k / 3) - 1) + oy;
        float pxf = (float)(t + (k % 3) - 1) + ox;
        float y0f = floorf(py), x0f = floorf(pxf);
        int y0 = (int)y0f, x0 = (int)x0f;
        float ly = py - y0f, lx = pxf - x0f;
        float w00 = (1.f - ly) * (1.f - lx) * mv;
        float w01 = (1.f - ly) * lx * mv;
        float w10 = ly * (1.f - lx) * mv;
        float w11 = ly * lx * mv;
        int y1 = y0 + 1, x1 = x0 + 1;
        bool vy0 = (y0 >= 0) && (y0 < 64), vy1 = (y1 >= 0) && (y1 < 64);
        bool vx0 = (x0 >= 0) && (x0 < 64), vx1 = (x1 >= 0) && (x1 < 64);
        int cy0 = min(max(y0, 0), 63), cy1 = min(max(y1, 0), 63);
        int cx0 = min(max(x0, 0), 63), cx1 = min(max(x1, 0), 63);
        swgt[t * 4 + 0] = (vy0 && vx0) ? w00 : 0.f;  slin[t * 4 + 0] = cy0 * 64 + cx0;
        swgt[t * 4 + 1] = (vy0 && vx1) ? w01 : 0.f;  slin[t * 4 + 1] = cy0 * 64 + cx1;
        swgt[t * 4 + 2] = (vy1 && vx0) ? w10 : 0.f;  slin[t * 4 + 2] = cy1 * 64 + cx0;
        swgt[t * 4 + 3] = (vy1 && vx1) ? w11 : 0.f;  slin[t * 4 + 3] = cy1 * 64 + cx1;
      }
      __syncthreads();
      float s0 = swgt[px * 4 + 0], s1 = swgt[px * 4 + 1];
      float s2 = swgt[px * 4 + 2], s3 = swgt[px * 4 + 3];
      int l0 = slin[px * 4 + 0], l1 = slin[px * 4 + 1];
      int l2 = slin[px * 4 + 2], l3 = slin[px * 4 + 3];
      const float* xg = x + ((size_t)b * CIN + g * CG) * 4096;
      for (int cl = 0; cl < 32; ++cl) {    // each oc-group gathers 32 channels
        int c = ocg * 32 + cl;
        const float* xp = xg + (size_t)c * 4096;
        float v = s0 * xp[l0] + s1 * xp[l1] + s2 * xp[l2] + s3 * xp[l3];
        vsm[c * 64 + px] = v;
      }
      for (int cc4 = 0; cc4 < 4; ++cc4) {  // 4 chunks of 32 channels
        __syncthreads();                   // vsm ready / wt safe to overwrite
        const float4* wbase =
            (const float4*)(wT + (((size_t)(g * 9 + k) * 128) + cc4 * 32) * 256);
        float4* wt4 = (float4*)wt;
        #pragma unroll
        for (int it = 0; it < 8; ++it) wt4[it * 256 + t] = wbase[it * 256 + t];
        __syncthreads();
        for (int cl = 0; cl < 32; ++cl) {
          float v = vsm[(cc4 * 32 + cl) * 64 + px];
          const float4* wrow = (const float4*)&wt[cl * 256 + ocg * 64];
          #pragma unroll
          for (int j4 = 0; j4 < 16; ++j4) {
            float4 wv = wrow[j4];
            acc[j4 * 4 + 0] += wv.x * v;
            acc[j4 * 4 + 1] += wv.y * v;
            acc[j4 * 4 + 2] += wv.z * v;
            acc[j4 * 4 + 3] += wv.w * v;
          }
        }
      }
    }
  }
  #pragma unroll
  for (int j = 0; j < 64; ++j) {
    int oc = ocg * 64 + j;
    float v = acc[j] * sc[oc] + sh[oc];
    out[(((size_t)b * COUT + oc) * 64 + y) * 64 + px] = fmaxf(v, 0.f);
  }
}

// ---------------------------------------------------------------------------
extern "C" void kernel_launch(void* const* d_in, const int* in_sizes, int n_in,
                              void* d_out, int out_size, void* d_ws, size_t ws_size,
                              hipStream_t stream) {
  const float* x     = (const float*)d_in[0];
  const float* w_off = (const float*)d_in[1];
  const float* b_off = (const float*)d_in[2];
  const float* w     = (const float*)d_in[3];
  const float* bconv = (const float*)d_in[4];
  const float* gamma = (const float*)d_in[5];
  const float* beta  = (const float*)d_in[6];
  const float* rmean = (const float*)d_in[7];
  const float* rvar  = (const float*)d_in[8];
  float* out = (float*)d_out;

  // workspace layout (floats): om[4*54*4096] | wT[18*128*256] | sc[256] | sh[256]
  float* om = (float*)d_ws;
  float* wT = om + 4 * 54 * 4096;
  float* sc = wT + 18 * 128 * 256;
  float* sh = sc + 256;

  prep_kernel<<<2304, 256, 0, stream>>>(w, bconv, gamma, beta, rmean, rvar, wT, sc, sh);
  offconv_kernel<<<4 * 64, 256, 0, stream>>>(x, w_off, b_off, om);
  dconv_kernel<<<4 * 64, 256, 0, stream>>>(x, om, wT, sc, sh, out);
}

// Round 2
// 288.518 us; speedup vs baseline: 3.8256x; 3.8256x over previous
//
#include <hip/hip_runtime.h>
#include <math.h>

typedef __bf16 bf16x8 __attribute__((ext_vector_type(8)));
typedef float  f32x4  __attribute__((ext_vector_type(4)));

#define MFMA16(a, b, c) __builtin_amdgcn_mfma_f32_16x16x32_bf16((a), (b), (c), 0, 0, 0)

// ---------------------------------------------------------------------------
// prep: wB[oc][ (g*9+k)*128 + c ] = bf16(w[oc][g*128+c][k])      (256 x 2304)
//       wOffB[oc][ k*256 + ci ]   = bf16(w_off[oc][ci][k])       (64  x 2304, oc>=54 zero)
//       sc/sh: folded BN (+conv bias)
// ---------------------------------------------------------------------------
__global__ __launch_bounds__(256) void prep_kernel(
    const float* __restrict__ w, const float* __restrict__ w_off,
    const float* __restrict__ bconv, const float* __restrict__ gamma,
    const float* __restrict__ beta, const float* __restrict__ mean,
    const float* __restrict__ var,
    __bf16* __restrict__ wB, __bf16* __restrict__ wOffB,
    float* __restrict__ sc, float* __restrict__ sh) {
  int i = blockIdx.x * 256 + threadIdx.x;     // grid covers 589824+147456 exactly
  if (i < 589824) {
    int oc = i / 2304, kidx = i % 2304;
    int gk = kidx >> 7, c = kidx & 127;
    int g = gk / 9, k = gk % 9;
    int ci = g * 128 + c;
    wB[i] = (__bf16)w[((size_t)oc * 256 + ci) * 9 + k];
  } else {
    int j = i - 589824;
    int oc = j / 2304, kidx = j % 2304;
    int k = kidx >> 8, ci = kidx & 255;
    wOffB[j] = (oc < 54) ? (__bf16)w_off[((size_t)oc * 256 + ci) * 9 + k]
                         : (__bf16)0.f;
  }
  if (i < 256) {
    float s = gamma[i] * rsqrtf(var[i] + 1e-5f);
    sc[i] = s;
    sh[i] = (bconv[i] - mean[i]) * s + beta[i];
  }
}

// ---------------------------------------------------------------------------
// offset/mask conv via MFMA: GEMM M=64(px row), N=64(54 oc padded), K=2304.
// One block per (b,y). 512 threads = 8 waves; wave = (px-half, oc-quad).
// Per tap: A-tile [64 px][256 ci] bf16 in LDS (shifted window), 8 K-chunks.
// ---------------------------------------------------------------------------
__global__ __launch_bounds__(512) void offconv_kernel(
    const float* __restrict__ x, const __bf16* __restrict__ wOffB,
    const float* __restrict__ b_off, float* __restrict__ om) {
  __shared__ __attribute__((aligned(16))) __bf16 atile[64 * 264];  // [px][ci], pad 8
  int t = threadIdx.x;
  int b = blockIdx.x >> 6, y = blockIdx.x & 63;
  int lane = t & 63, wv = t >> 6;
  int l15 = lane & 15, quad = lane >> 4;
  int mh = wv & 1;                 // px half (0: px 0..31, 1: px 32..63)
  int ocb = (wv >> 1) * 16;        // oc base of this wave's N=16 slice
  int px = lane;                   // gather mapping: lane = pixel column

  f32x4 acc0 = {0.f, 0.f, 0.f, 0.f};
  f32x4 acc1 = {0.f, 0.f, 0.f, 0.f};

  for (int tap = 0; tap < 9; ++tap) {
    int dy = tap / 3 - 1, dx = tap % 3 - 1;
    int y2 = y + dy, x2 = px + dx;
    bool inb = (y2 >= 0 && y2 < 64 && x2 >= 0 && x2 < 64);
    const float* xp = x + (((size_t)b * 256) * 64 + (y2 < 0 ? 0 : y2)) * 64
                        + (x2 < 0 ? 0 : (x2 > 63 ? 63 : x2));
    __syncthreads();               // previous tap's MFMA reads done
    // each wave fills ci in [wv*32, wv*32+32), packed 8-wide b128 stores
    for (int h8 = 0; h8 < 4; ++h8) {
      union { __bf16 h[8]; bf16x8 v; } u;
      #pragma unroll
      for (int j = 0; j < 8; ++j) {
        int c = wv * 32 + h8 * 8 + j;
        float v = inb ? xp[(size_t)c * 4096] : 0.f;
        u.h[j] = (__bf16)v;
      }
      *(bf16x8*)&atile[px * 264 + wv * 32 + h8 * 8] = u.v;
    }
    __syncthreads();
    const __bf16* wrow = wOffB + (size_t)(ocb + l15) * 2304 + tap * 256 + quad * 8;
    const __bf16* arow = atile + (mh * 32 + l15) * 264 + quad * 8;
    #pragma unroll
    for (int ch = 0; ch < 8; ++ch) {
      bf16x8 bf = *(const bf16x8*)(wrow + ch * 32);
      bf16x8 a0 = *(const bf16x8*)(arow + ch * 32);
      bf16x8 a1 = *(const bf16x8*)(arow + 16 * 264 + ch * 32);
      acc0 = MFMA16(a0, bf, acc0);
      acc1 = MFMA16(a1, bf, acc1);
    }
  }
  int oc = ocb + l15;
  if (oc < 54) {
    float bo = b_off[oc];
    #pragma unroll
    for (int fm = 0; fm < 2; ++fm) {
      f32x4 v = fm ? acc1 : acc0;
      f32x4 r = {v.x + bo, v.y + bo, v.z + bo, v.w + bo};
      int pxs = mh * 32 + fm * 16 + quad * 4;
      *(f32x4*)(om + (((size_t)b * 54 + oc) * 64 + y) * 64 + pxs) = r;
    }
  }
}

// ---------------------------------------------------------------------------
// deformable conv + BN + ReLU via MFMA: GEMM M=64, N=256, K=2304.
// One block per (b,y). 512 threads = 8 waves; wave w -> oc [w*32, w*32+32).
// Per tap: bilinear-gather A-tile [64 px][128 c] bf16, 4 K-chunks of 32.
// ---------------------------------------------------------------------------
__global__ __launch_bounds__(512) void dconv_kernel(
    const float* __restrict__ x, const float* __restrict__ om,
    const __bf16* __restrict__ wB, const float* __restrict__ sc,
    const float* __restrict__ sh, float* __restrict__ out) {
  __shared__ float swgt[18 * 64 * 4];
  __shared__ int   slin[18 * 64 * 4];
  __shared__ __attribute__((aligned(16))) __bf16 atile[64 * 136];  // [px][c], pad 8
  int t = threadIdx.x;
  int b = blockIdx.x >> 6, y = blockIdx.x & 63;
  int lane = t & 63, wv = t >> 6;
  int l15 = lane & 15, quad = lane >> 4;
  int ocb = wv * 32;
  int px = lane;

  // phase 1: per-(tap,px) bilinear corner weights (x sigmoid mask) + indices
  for (int i = t; i < 18 * 64; i += 512) {
    int gk = i >> 6, p = i & 63;
    int g = gk / 9, k = gk - g * 9;
    size_t obase = (size_t)b * 54 * 4096 + (size_t)y * 64 + p;
    float oy = om[obase + (size_t)gk * 4096];
    float ox = om[obase + (size_t)(18 + gk) * 4096];
    float mz = om[obase + (size_t)(36 + gk) * 4096];
    float mv = 1.f / (1.f + expf(-mz));
    float py  = (float)(y + (k / 3) - 1) + oy;
    float pxf = (float)(p + (k % 3) - 1) + ox;
    float y0f = floorf(py), x0f = floorf(pxf);
    int y0 = (int)y0f, x0 = (int)x0f;
    float ly = py - y0f, lx = pxf - x0f;
    int y1 = y0 + 1, x1 = x0 + 1;
    bool vy0 = (y0 >= 0) && (y0 < 64), vy1 = (y1 >= 0) && (y1 < 64);
    bool vx0 = (x0 >= 0) && (x0 < 64), vx1 = (x1 >= 0) && (x1 < 64);
    int cy0 = min(max(y0, 0), 63), cy1 = min(max(y1, 0), 63);
    int cx0 = min(max(x0, 0), 63), cx1 = min(max(x1, 0), 63);
    swgt[i * 4 + 0] = (vy0 && vx0) ? (1.f - ly) * (1.f - lx) * mv : 0.f;
    swgt[i * 4 + 1] = (vy0 && vx1) ? (1.f - ly) * lx * mv : 0.f;
    swgt[i * 4 + 2] = (vy1 && vx0) ? ly * (1.f - lx) * mv : 0.f;
    swgt[i * 4 + 3] = (vy1 && vx1) ? ly * lx * mv : 0.f;
    slin[i * 4 + 0] = cy0 * 64 + cx0;
    slin[i * 4 + 1] = cy0 * 64 + cx1;
    slin[i * 4 + 2] = cy1 * 64 + cx0;
    slin[i * 4 + 3] = cy1 * 64 + cx1;
  }

  f32x4 acc[4][2];
  #pragma unroll
  for (int fm = 0; fm < 4; ++fm)
    #pragma unroll
    for (int fn = 0; fn < 2; ++fn)
      acc[fm][fn] = (f32x4){0.f, 0.f, 0.f, 0.f};

  __syncthreads();

  for (int gk = 0; gk < 18; ++gk) {
    int g = gk / 9;
    float s0 = swgt[(gk * 64 + px) * 4 + 0], s1 = swgt[(gk * 64 + px) * 4 + 1];
    float s2 = swgt[(gk * 64 + px) * 4 + 2], s3 = swgt[(gk * 64 + px) * 4 + 3];
    int l0 = slin[(gk * 64 + px) * 4 + 0], l1 = slin[(gk * 64 + px) * 4 + 1];
    int l2 = slin[(gk * 64 + px) * 4 + 2], l3 = slin[(gk * 64 + px) * 4 + 3];
    const float* xg = x + ((size_t)b * 256 + g * 128) * 4096;
    __syncthreads();               // previous tap's MFMA reads done
    // each wave gathers c in [wv*16, wv*16+16)
    #pragma unroll
    for (int h8 = 0; h8 < 2; ++h8) {
      union { __bf16 h[8]; bf16x8 v; } u;
      #pragma unroll
      for (int j = 0; j < 8; ++j) {
        int c = wv * 16 + h8 * 8 + j;
        const float* cp = xg + (size_t)c * 4096;
        u.h[j] = (__bf16)(s0 * cp[l0] + s1 * cp[l1] + s2 * cp[l2] + s3 * cp[l3]);
      }
      *(bf16x8*)&atile[px * 136 + wv * 16 + h8 * 8] = u.v;
    }
    __syncthreads();
    const __bf16* arow = atile + l15 * 136 + quad * 8;
    const __bf16* wr0 = wB + (size_t)(ocb + l15) * 2304 + gk * 128 + quad * 8;
    #pragma unroll
    for (int ch = 0; ch < 4; ++ch) {
      bf16x8 b0 = *(const bf16x8*)(wr0 + ch * 32);
      bf16x8 b1 = *(const bf16x8*)(wr0 + (size_t)16 * 2304 + ch * 32);
      #pragma unroll
      for (int fm = 0; fm < 4; ++fm) {
        bf16x8 a = *(const bf16x8*)(arow + fm * 16 * 136 + ch * 32);
        acc[fm][0] = MFMA16(a, b0, acc[fm][0]);
        acc[fm][1] = MFMA16(a, b1, acc[fm][1]);
      }
    }
  }

  #pragma unroll
  for (int fm = 0; fm < 4; ++fm) {
    #pragma unroll
    for (int fn = 0; fn < 2; ++fn) {
      int oc = ocb + fn * 16 + l15;
      float s = sc[oc], h = sh[oc];
      f32x4 v = acc[fm][fn];
      f32x4 r = {fmaxf(v.x * s + h, 0.f), fmaxf(v.y * s + h, 0.f),
                 fmaxf(v.z * s + h, 0.f), fmaxf(v.w * s + h, 0.f)};
      int pxs = fm * 16 + quad * 4;
      *(f32x4*)(out + (((size_t)b * 256 + oc) * 64 + y) * 64 + pxs) = r;
    }
  }
}

// ---------------------------------------------------------------------------
extern "C" void kernel_launch(void* const* d_in, const int* in_sizes, int n_in,
                              void* d_out, int out_size, void* d_ws, size_t ws_size,
                              hipStream_t stream) {
  const float* x     = (const float*)d_in[0];
  const float* w_off = (const float*)d_in[1];
  const float* b_off = (const float*)d_in[2];
  const float* w     = (const float*)d_in[3];
  const float* bconv = (const float*)d_in[4];
  const float* gamma = (const float*)d_in[5];
  const float* beta  = (const float*)d_in[6];
  const float* rmean = (const float*)d_in[7];
  const float* rvar  = (const float*)d_in[8];
  float* out = (float*)d_out;

  // ws layout (bytes): om f32[4*54*4096] @0 | wB bf16[256*2304] @3538944 |
  //                    wOffB bf16[64*2304] @4718592 | sc @5013504 | sh @5014528
  float*  om    = (float*)d_ws;
  __bf16* wB    = (__bf16*)((char*)d_ws + 3538944);
  __bf16* wOffB = (__bf16*)((char*)d_ws + 4718592);
  float*  sc    = (float*)((char*)d_ws + 5013504);
  float*  sh    = (float*)((char*)d_ws + 5014528);

  prep_kernel<<<2880, 256, 0, stream>>>(w, w_off, bconv, gamma, beta, rmean, rvar,
                                        wB, wOffB, sc, sh);
  offconv_kernel<<<4 * 64, 512, 0, stream>>>(x, wOffB, b_off, om);
  dconv_kernel<<<4 * 64, 512, 0, stream>>>(x, om, wB, sc, sh, out);
}

// Round 4
// 148.201 us; speedup vs baseline: 7.4476x; 1.9468x over previous
//
#include <hip/hip_runtime.h>
#include <math.h>

typedef __bf16 bf16x8 __attribute__((ext_vector_type(8)));
typedef __bf16 bf16x4 __attribute__((ext_vector_type(4)));
typedef __bf16 bf16x2 __attribute__((ext_vector_type(2)));
typedef float  f32x4  __attribute__((ext_vector_type(4)));

#define MFMA16(a, b, c) __builtin_amdgcn_mfma_f32_16x16x32_bf16((a), (b), (c), 0, 0, 0)

// ---------------------------------------------------------------------------
// xpose: x [b][c][y][x] fp32  ->  xT [b][y][x][c] bf16   (NHWC for coalesced
// channel-contiguous gathers). One block per (b,y); LDS 64x65 tile.
// ---------------------------------------------------------------------------
__global__ __launch_bounds__(256) void xpose_kernel(
    const float* __restrict__ x, __bf16* __restrict__ xT) {
  __shared__ float xs[64][65];
  int t = threadIdx.x;
  int b = blockIdx.x >> 6, y = blockIdx.x & 63;
  for (int cc = 0; cc < 4; ++cc) {
    __syncthreads();
    for (int i = t; i < 4096; i += 256) {
      int cl = i >> 6, xc = i & 63;
      xs[cl][xc] = x[(((size_t)b * 256 + cc * 64 + cl) * 64 + y) * 64 + xc];
    }
    __syncthreads();
    for (int i = t; i < 4096; i += 256) {
      int xc = i >> 6, cl = i & 63;
      xT[(((size_t)b * 64 + y) * 64 + xc) * 256 + cc * 64 + cl] = (__bf16)xs[cl][xc];
    }
  }
}

// ---------------------------------------------------------------------------
// prep: weights -> exact MFMA B-fragment order (one coalesced 1KB wave-load
// per fragment), plus folded BN scale/shift.
// wFragD[((gk*4+kc)*16+ocb)*512 + lane*8 + j] = w[oc=ocb*16+(lane&15)]
//        [g*128 + kc*32 + (lane>>4)*8 + j][ktap],  gk = g*9+ktap
// wFragO[((tap*8+kc)*4+ocb)*512 + lane*8 + j] = w_off[oc=ocb*16+(lane&15)]
//        [kc*32 + (lane>>4)*8 + j][tap]   (oc>=54 zero-padded)
// ---------------------------------------------------------------------------
__global__ __launch_bounds__(256) void prep_kernel(
    const float* __restrict__ w, const float* __restrict__ w_off,
    const float* __restrict__ bconv, const float* __restrict__ gamma,
    const float* __restrict__ beta, const float* __restrict__ mean,
    const float* __restrict__ var,
    __bf16* __restrict__ wFragD, __bf16* __restrict__ wFragO,
    float* __restrict__ sc, float* __restrict__ sh) {
  int i = blockIdx.x * 256 + threadIdx.x;   // grid covers 589824+147456 exactly
  if (i < 589824) {
    int j = i & 7, lane = (i >> 3) & 63, ocb = (i >> 9) & 15;
    int kc = (i >> 13) & 3, gk = i >> 15;
    int klocal = (lane >> 4) * 8 + j;
    int oc = ocb * 16 + (lane & 15);
    int c = kc * 32 + klocal;
    int g = gk / 9, ktap = gk % 9;
    wFragD[i] = (__bf16)w[((size_t)oc * 256 + g * 128 + c) * 9 + ktap];
  } else {
    int i2 = i - 589824;
    int j = i2 & 7, lane = (i2 >> 3) & 63, ocb = (i2 >> 9) & 3;
    int kc = (i2 >> 11) & 7, tap = i2 >> 14;
    int klocal = (lane >> 4) * 8 + j;
    int oc = ocb * 16 + (lane & 15);
    int ci = kc * 32 + klocal;
    wFragO[i2] = (oc < 54) ? (__bf16)w_off[((size_t)oc * 256 + ci) * 9 + tap]
                           : (__bf16)0.f;
  }
  if (i < 256) {
    float s = gamma[i] * rsqrtf(var[i] + 1e-5f);
    sc[i] = s;
    sh[i] = (bconv[i] - mean[i]) * s + beta[i];
  }
}

// ---------------------------------------------------------------------------
// offset/mask conv via MFMA, NHWC input. One block per (b,y), 512 thr/8 waves.
// Software-pipelined: sync -> issue tap+1 loads -> MFMA(buf cur) -> write nxt.
// ---------------------------------------------------------------------------
__global__ __launch_bounds__(512) void offconv_kernel(
    const __bf16* __restrict__ xT, const __bf16* __restrict__ wFragO,
    const float* __restrict__ b_off, float* __restrict__ om) {
  __shared__ __attribute__((aligned(16))) __bf16 atile[2][64 * 264];
  int t = threadIdx.x;
  int b = blockIdx.x >> 6, y = blockIdx.x & 63;
  int lane = t & 63, wv = t >> 6;
  int l15 = lane & 15, quad = lane >> 4;
  int mh = wv & 1, ocq = wv >> 1;
  const __bf16* xTb = xT + (size_t)b * 64 * 64 * 256;

  f32x4 acc0 = {0.f, 0.f, 0.f, 0.f};
  f32x4 acc1 = {0.f, 0.f, 0.f, 0.f};
  const bf16x4 z4 = {(__bf16)0.f, (__bf16)0.f, (__bf16)0.f, (__bf16)0.f};

  // prologue: tap 0 (dy=-1,dx=-1) -> atile[0]
  {
    int y2 = y - 1;
    #pragma unroll
    for (int pp = 0; pp < 8; ++pp) {
      int p = wv * 8 + pp, x2 = p - 1;
      bool inb = (y2 >= 0) && (x2 >= 0);
      bf16x4 v = inb ? *(const bf16x4*)(xTb + (((size_t)y2 * 64 + x2) * 256) + 4 * lane)
                     : z4;
      *(bf16x4*)&atile[0][p * 264 + 4 * lane] = v;
    }
  }

  for (int tap = 0; tap < 9; ++tap) {
    __syncthreads();
    bf16x4 g[8];
    bool inb[8];
    if (tap < 8) {                       // issue loads for tap+1
      int dy = (tap + 1) / 3 - 1, dx = (tap + 1) % 3 - 1;
      int y2 = y + dy;
      #pragma unroll
      for (int pp = 0; pp < 8; ++pp) {
        int p = wv * 8 + pp, x2 = p + dx;
        inb[pp] = (y2 >= 0) && (y2 < 64) && (x2 >= 0) && (x2 < 64);
        int cy = inb[pp] ? y2 : 0, cx = inb[pp] ? x2 : 0;
        g[pp] = *(const bf16x4*)(xTb + (((size_t)cy * 64 + cx) * 256) + 4 * lane);
      }
    }
    // MFMA on atile[tap&1]
    const __bf16* arow = atile[tap & 1] + (mh * 32 + l15) * 264 + quad * 8;
    const __bf16* bbase = wFragO + ((size_t)(tap * 8) * 4 + ocq) * 512 + lane * 8;
    #pragma unroll
    for (int kc = 0; kc < 8; ++kc) {
      bf16x8 bf = *(const bf16x8*)(bbase + (size_t)kc * 4 * 512);
      bf16x8 a0 = *(const bf16x8*)(arow + kc * 32);
      bf16x8 a1 = *(const bf16x8*)(arow + 16 * 264 + kc * 32);
      acc0 = MFMA16(a0, bf, acc0);
      acc1 = MFMA16(a1, bf, acc1);
    }
    if (tap < 8) {                       // write tap+1 -> other buffer
      __bf16* dst = atile[(tap + 1) & 1];
      #pragma unroll
      for (int pp = 0; pp < 8; ++pp) {
        bf16x4 v = inb[pp] ? g[pp] : z4;
        *(bf16x4*)&dst[(wv * 8 + pp) * 264 + 4 * lane] = v;
      }
    }
  }

  int oc = ocq * 16 + l15;
  if (oc < 54) {
    float bo = b_off[oc];
    #pragma unroll
    for (int fm = 0; fm < 2; ++fm) {
      f32x4 v = fm ? acc1 : acc0;
      f32x4 r = {v.x + bo, v.y + bo, v.z + bo, v.w + bo};
      int pxs = mh * 32 + fm * 16 + quad * 4;
      *(f32x4*)(om + (((size_t)b * 54 + oc) * 64 + y) * 64 + pxs) = r;
    }
  }
}

// ---------------------------------------------------------------------------
// deformable conv + BN + ReLU via MFMA, NHWC gather (lane = channel pair).
// One block per (b,y), 512 thr/8 waves. Same software pipeline.
// ---------------------------------------------------------------------------
__global__ __launch_bounds__(512) void dconv_kernel(
    const __bf16* __restrict__ xT, const float* __restrict__ om,
    const __bf16* __restrict__ wFragD, const float* __restrict__ sc,
    const float* __restrict__ sh, float* __restrict__ out) {
  __shared__ float swgt[18 * 64 * 4];
  __shared__ int   slin[18 * 64 * 4];
  __shared__ __attribute__((aligned(16))) __bf16 atile[2][64 * 136];
  int t = threadIdx.x;
  int b = blockIdx.x >> 6, y = blockIdx.x & 63;
  int lane = t & 63, wv = t >> 6;
  int l15 = lane & 15, quad = lane >> 4;
  const __bf16* xTb = xT + (size_t)b * 64 * 64 * 256;

  // phase 1: bilinear corner weights (x sigmoid mask) + NHWC spatial offsets
  for (int i = t; i < 18 * 64; i += 512) {
    int gk = i >> 6, p = i & 63;
    int k = gk % 9;
    size_t obase = (size_t)b * 54 * 4096 + (size_t)y * 64 + p;
    float oy = om[obase + (size_t)gk * 4096];
    float ox = om[obase + (size_t)(18 + gk) * 4096];
    float mz = om[obase + (size_t)(36 + gk) * 4096];
    float mv = 1.f / (1.f + expf(-mz));
    float py  = (float)(y + (k / 3) - 1) + oy;
    float pxf = (float)(p + (k % 3) - 1) + ox;
    float y0f = floorf(py), x0f = floorf(pxf);
    int y0 = (int)y0f, x0 = (int)x0f;
    float ly = py - y0f, lx = pxf - x0f;
    int y1 = y0 + 1, x1 = x0 + 1;
    bool vy0 = (y0 >= 0) && (y0 < 64), vy1 = (y1 >= 0) && (y1 < 64);
    bool vx0 = (x0 >= 0) && (x0 < 64), vx1 = (x1 >= 0) && (x1 < 64);
    int cy0 = min(max(y0, 0), 63), cy1 = min(max(y1, 0), 63);
    int cx0 = min(max(x0, 0), 63), cx1 = min(max(x1, 0), 63);
    swgt[i * 4 + 0] = (vy0 && vx0) ? (1.f - ly) * (1.f - lx) * mv : 0.f;
    swgt[i * 4 + 1] = (vy0 && vx1) ? (1.f - ly) * lx * mv : 0.f;
    swgt[i * 4 + 2] = (vy1 && vx0) ? ly * (1.f - lx) * mv : 0.f;
    swgt[i * 4 + 3] = (vy1 && vx1) ? ly * lx * mv : 0.f;
    slin[i * 4 + 0] = (cy0 * 64 + cx0) * 256;
    slin[i * 4 + 1] = (cy0 * 64 + cx1) * 256;
    slin[i * 4 + 2] = (cy1 * 64 + cx0) * 256;
    slin[i * 4 + 3] = (cy1 * 64 + cx1) * 256;
  }

  f32x4 acc[4][2];
  #pragma unroll
  for (int fm = 0; fm < 4; ++fm)
    #pragma unroll
    for (int fn = 0; fn < 2; ++fn)
      acc[fm][fn] = (f32x4){0.f, 0.f, 0.f, 0.f};

  __syncthreads();                        // phase-1 tables visible

  // prologue: gather tap 0 (gk=0, g=0) -> atile[0]
  {
    const __bf16* xg = xTb + 2 * lane;    // g=0
    #pragma unroll
    for (int pp = 0; pp < 8; ++pp) {
      int p = wv * 8 + pp, base = p * 4;  // gk=0
      float v0 = 0.f, v1 = 0.f;
      #pragma unroll
      for (int i = 0; i < 4; ++i) {
        float s = swgt[base + i];
        bf16x2 vv = *(const bf16x2*)(xg + slin[base + i]);
        v0 += s * (float)vv.x;
        v1 += s * (float)vv.y;
      }
      bf16x2 o = {(__bf16)v0, (__bf16)v1};
      *(bf16x2*)&atile[0][p * 136 + 2 * lane] = o;
    }
  }

  for (int gk = 0; gk < 18; ++gk) {
    __syncthreads();
    bf16x2 gv[8][4];
    float gs[8][4];
    if (gk < 17) {                        // issue gather loads for tap gk+1
      int gn = gk + 1;
      const __bf16* xg = xTb + (gn / 9) * 128 + 2 * lane;
      #pragma unroll
      for (int pp = 0; pp < 8; ++pp) {
        int p = wv * 8 + pp, base = (gn * 64 + p) * 4;
        #pragma unroll
        for (int i = 0; i < 4; ++i) {
          gs[pp][i] = swgt[base + i];
          gv[pp][i] = *(const bf16x2*)(xg + slin[base + i]);
        }
      }
    }
    // MFMA on atile[gk&1]; B-frags are single coalesced 1KB wave-loads
    const __bf16* arow = atile[gk & 1] + l15 * 136 + quad * 8;
    const __bf16* bbase = wFragD + ((size_t)(gk * 4) * 16 + wv * 2) * 512 + lane * 8;
    #pragma unroll
    for (int kc = 0; kc < 4; ++kc) {
      bf16x8 b0 = *(const bf16x8*)(bbase + (size_t)kc * 16 * 512);
      bf16x8 b1 = *(const bf16x8*)(bbase + (size_t)kc * 16 * 512 + 512);
      #pragma unroll
      for (int fm = 0; fm < 4; ++fm) {
        bf16x8 a = *(const bf16x8*)(arow + fm * 16 * 136 + kc * 32);
        acc[fm][0] = MFMA16(a, b0, acc[fm][0]);
        acc[fm][1] = MFMA16(a, b1, acc[fm][1]);
      }
    }
    if (gk < 17) {                        // combine + write tap gk+1
      __bf16* dst = atile[(gk + 1) & 1];
      #pragma unroll
      for (int pp = 0; pp < 8; ++pp) {
        float v0 = gs[pp][0] * (float)gv[pp][0].x + gs[pp][1] * (float)gv[pp][1].x
                 + gs[pp][2] * (float)gv[pp][2].x + gs[pp][3] * (float)gv[pp][3].x;
        float v1 = gs[pp][0] * (float)gv[pp][0].y + gs[pp][1] * (float)gv[pp][1].y
                 + gs[pp][2] * (float)gv[pp][2].y + gs[pp][3] * (float)gv[pp][3].y;
        bf16x2 o = {(__bf16)v0, (__bf16)v1};
        *(bf16x2*)&dst[(wv * 8 + pp) * 136 + 2 * lane] = o;
      }
    }
  }

  #pragma unroll
  for (int fm = 0; fm < 4; ++fm) {
    #pragma unroll
    for (int fn = 0; fn < 2; ++fn) {
      int oc = wv * 32 + fn * 16 + l15;
      float s = sc[oc], h = sh[oc];
      f32x4 v = acc[fm][fn];
      f32x4 r = {fmaxf(v.x * s + h, 0.f), fmaxf(v.y * s + h, 0.f),
                 fmaxf(v.z * s + h, 0.f), fmaxf(v.w * s + h, 0.f)};
      int pxs = fm * 16 + quad * 4;
      *(f32x4*)(out + (((size_t)b * 256 + oc) * 64 + y) * 64 + pxs) = r;
    }
  }
}

// ---------------------------------------------------------------------------
extern "C" void kernel_launch(void* const* d_in, const int* in_sizes, int n_in,
                              void* d_out, int out_size, void* d_ws, size_t ws_size,
                              hipStream_t stream) {
  const float* x     = (const float*)d_in[0];
  const float* w_off = (const float*)d_in[1];
  const float* b_off = (const float*)d_in[2];
  const float* w     = (const float*)d_in[3];
  const float* bconv = (const float*)d_in[4];
  const float* gamma = (const float*)d_in[5];
  const float* beta  = (const float*)d_in[6];
  const float* rmean = (const float*)d_in[7];
  const float* rvar  = (const float*)d_in[8];
  float* out = (float*)d_out;

  // ws layout (BYTE offsets; sizes in bytes):
  // om     f32 [884736]    @ 0           size 3,538,944
  // xT     bf16[4194304]   @ 3,538,944   size 8,388,608   (round-3 bug: was
  //                                       sized by element count -> overlapped)
  // wFragD bf16[589824]    @ 11,927,552  size 1,179,648
  // wFragO bf16[147456]    @ 13,107,200  size   294,912
  // sc     f32 [256]       @ 13,402,112  size     1,024
  // sh     f32 [256]       @ 13,403,136  size     1,024     total ~12.8 MiB
  float*  om     = (float*)d_ws;
  __bf16* xT     = (__bf16*)((char*)d_ws + 3538944);
  __bf16* wFragD = (__bf16*)((char*)d_ws + 11927552);
  __bf16* wFragO = (__bf16*)((char*)d_ws + 13107200);
  float*  sc     = (float*)((char*)d_ws + 13402112);
  float*  sh     = (float*)((char*)d_ws + 13403136);

  xpose_kernel<<<4 * 64, 256, 0, stream>>>(x, xT);
  prep_kernel<<<2880, 256, 0, stream>>>(w, w_off, bconv, gamma, beta, rmean, rvar,
                                        wFragD, wFragO, sc, sh);
  offconv_kernel<<<4 * 64, 512, 0, stream>>>(xT, wFragO, b_off, om);
  dconv_kernel<<<4 * 64, 512, 0, stream>>>(xT, om, wFragD, sc, sh, out);
}

// Round 5
// 138.159 us; speedup vs baseline: 7.9890x; 1.0727x over previous
//
#include <hip/hip_runtime.h>
#include <math.h>

typedef __bf16 bf16x8 __attribute__((ext_vector_type(8)));
typedef float  f32x4  __attribute__((ext_vector_type(4)));
typedef int    i32x4  __attribute__((ext_vector_type(4)));

#define MFMA16(a, b, c) __builtin_amdgcn_mfma_f32_16x16x32_bf16((a), (b), (c), 0, 0, 0)

// A-tile layout: row stride 128 (no pad), 16B chunks XOR-swizzled by row to
// break the 4-stride bank pattern (r4: 2.36M SQ_LDS_BANK_CONFLICT).
#define ATIDX(r, c) ((r) * 128 + (((c) ^ ((r) & 7)) * 8))

// ---------------------------------------------------------------------------
// xpose: x [b][c][y][x] fp32 -> xT [b][y][x][c] bf16. One block per (b,y,cc);
// grid 1024 (4 blocks/CU) for latency hiding.
// ---------------------------------------------------------------------------
__global__ __launch_bounds__(256) void xpose_kernel(
    const float* __restrict__ x, __bf16* __restrict__ xT) {
  __shared__ float xs[64][65];
  int t = threadIdx.x;
  int b = blockIdx.x >> 8, y = (blockIdx.x >> 2) & 63, cc = blockIdx.x & 3;
  for (int i = t; i < 4096; i += 256) {
    int cl = i >> 6, xc = i & 63;
    xs[cl][xc] = x[(((size_t)b * 256 + cc * 64 + cl) * 64 + y) * 64 + xc];
  }
  __syncthreads();
  for (int i = t; i < 4096; i += 256) {
    int xc = i >> 6, cl = i & 63;
    xT[(((size_t)b * 64 + y) * 64 + xc) * 256 + cc * 64 + cl] = (__bf16)xs[cl][xc];
  }
}

// ---------------------------------------------------------------------------
// prep: weights -> exact MFMA B-fragment order (unchanged from r4), BN fold.
// ---------------------------------------------------------------------------
__global__ __launch_bounds__(256) void prep_kernel(
    const float* __restrict__ w, const float* __restrict__ w_off,
    const float* __restrict__ bconv, const float* __restrict__ gamma,
    const float* __restrict__ beta, const float* __restrict__ mean,
    const float* __restrict__ var,
    __bf16* __restrict__ wFragD, __bf16* __restrict__ wFragO,
    float* __restrict__ sc, float* __restrict__ sh) {
  int i = blockIdx.x * 256 + threadIdx.x;
  if (i < 589824) {
    int j = i & 7, lane = (i >> 3) & 63, ocb = (i >> 9) & 15;
    int kc = (i >> 13) & 3, gk = i >> 15;
    int klocal = (lane >> 4) * 8 + j;
    int oc = ocb * 16 + (lane & 15);
    int c = kc * 32 + klocal;
    int g = gk / 9, ktap = gk % 9;
    wFragD[i] = (__bf16)w[((size_t)oc * 256 + g * 128 + c) * 9 + ktap];
  } else {
    int i2 = i - 589824;
    int j = i2 & 7, lane = (i2 >> 3) & 63, ocb = (i2 >> 9) & 3;
    int kc = (i2 >> 11) & 7, tap = i2 >> 14;
    int klocal = (lane >> 4) * 8 + j;
    int oc = ocb * 16 + (lane & 15);
    int ci = kc * 32 + klocal;
    wFragO[i2] = (oc < 54) ? (__bf16)w_off[((size_t)oc * 256 + ci) * 9 + tap]
                           : (__bf16)0.f;
  }
  if (i < 256) {
    float s = gamma[i] * rsqrtf(var[i] + 1e-5f);
    sc[i] = s;
    sh[i] = (bconv[i] - mean[i]) * s + beta[i];
  }
}

// ---------------------------------------------------------------------------
// offset/mask conv: stage 3 zero-padded rows (66 px x 256 ch bf16, swizzled)
// in LDS ONCE, then 9 taps of pure MFMA with shifted-window A reads.
// No barriers in the tap loop. One block per (b,y), 512 thr / 8 waves.
// ---------------------------------------------------------------------------
__global__ __launch_bounds__(512) void offconv_kernel(
    const __bf16* __restrict__ xT, const __bf16* __restrict__ wFragO,
    const float* __restrict__ b_off, float* __restrict__ om) {
  __shared__ __attribute__((aligned(16))) __bf16 rowbuf[3 * 66 * 256];  // 99 KB
  int t = threadIdx.x;
  int b = blockIdx.x >> 6, y = blockIdx.x & 63;
  int lane = t & 63, wv = t >> 6;
  int l15 = lane & 15, quad = lane >> 4;
  int mh = wv & 1, ocq = wv >> 1;
  const __bf16* xTb = xT + (size_t)b * 64 * 64 * 256;
  bf16x8 z8;
  #pragma unroll
  for (int e = 0; e < 8; ++e) z8[e] = (__bf16)0.f;

  // stage: rowbuf[dy][px66][ch], px66 = x+1 (cols 0,65 are zero pad)
  for (int i = t; i < 3 * 66 * 32; i += 512) {
    int c = i & 31, px66 = (i >> 5) % 66, dy = i / 2112;
    int y2 = y + dy - 1, x2 = px66 - 1;
    bf16x8 v = z8;
    if (y2 >= 0 && y2 < 64 && x2 >= 0 && x2 < 64)
      v = *(const bf16x8*)(xTb + ((size_t)y2 * 64 + x2) * 256 + c * 8);
    *(bf16x8*)&rowbuf[dy * 16896 + px66 * 256 + ((c ^ (px66 & 7)) * 8)] = v;
  }
  __syncthreads();

  f32x4 acc0 = {0.f, 0.f, 0.f, 0.f};
  f32x4 acc1 = {0.f, 0.f, 0.f, 0.f};
  for (int tap = 0; tap < 9; ++tap) {
    int dy = tap / 3, dxs = tap % 3;
    const __bf16* bb = wFragO + ((size_t)(tap * 8) * 4 + ocq) * 512 + lane * 8;
    bf16x8 Bf[8];
    #pragma unroll
    for (int kc = 0; kc < 8; ++kc)
      Bf[kc] = *(const bf16x8*)(bb + (size_t)kc * 4 * 512);
    int p0 = mh * 32 + l15 + dxs, p1 = p0 + 16;
    const __bf16* rb = rowbuf + dy * 16896;
    #pragma unroll
    for (int kc = 0; kc < 8; ++kc) {
      int c = kc * 4 + quad;
      bf16x8 a0 = *(const bf16x8*)&rb[p0 * 256 + ((c ^ (p0 & 7)) * 8)];
      bf16x8 a1 = *(const bf16x8*)&rb[p1 * 256 + ((c ^ (p1 & 7)) * 8)];
      acc0 = MFMA16(a0, Bf[kc], acc0);
      acc1 = MFMA16(a1, Bf[kc], acc1);
    }
  }

  int oc = ocq * 16 + l15;
  if (oc < 54) {
    float bo = b_off[oc];
    #pragma unroll
    for (int fm = 0; fm < 2; ++fm) {
      f32x4 v = fm ? acc1 : acc0;
      f32x4 r = {v.x + bo, v.y + bo, v.z + bo, v.w + bo};
      int pxs = mh * 32 + fm * 16 + quad * 4;
      *(f32x4*)(om + (((size_t)b * 54 + oc) * 64 + y) * 64 + pxs) = r;
    }
  }
}

// ---------------------------------------------------------------------------
// deformable conv + BN + ReLU. One block per (b,y), 512 thr / 8 waves.
// Fat gathers: 16 lanes/px read bf16x8 (8 consecutive NHWC channels) per
// corner. Cross-tap B-frag register prefetch. Swizzled double-buffered A-tile.
// ---------------------------------------------------------------------------
__global__ __launch_bounds__(512) void dconv_kernel(
    const __bf16* __restrict__ xT, const float* __restrict__ om,
    const __bf16* __restrict__ wFragD, const float* __restrict__ sc,
    const float* __restrict__ sh, float* __restrict__ out) {
  __shared__ f32x4 swgtv[18 * 64];
  __shared__ i32x4 slinv[18 * 64];
  __shared__ __attribute__((aligned(16))) __bf16 atile[2][64 * 128];
  int t = threadIdx.x;
  int b = blockIdx.x >> 6, y = blockIdx.x & 63;
  int lane = t & 63, wv = t >> 6;
  int l15 = lane & 15, quad = lane >> 4;
  const __bf16* xTb = xT + (size_t)b * 64 * 64 * 256;

  // phase 1: bilinear corner weights (x sigmoid mask) + NHWC offsets, packed
  for (int i = t; i < 18 * 64; i += 512) {
    int gk = i >> 6, p = i & 63;
    int k = gk % 9;
    size_t obase = (size_t)b * 54 * 4096 + (size_t)y * 64 + p;
    float oy = om[obase + (size_t)gk * 4096];
    float ox = om[obase + (size_t)(18 + gk) * 4096];
    float mz = om[obase + (size_t)(36 + gk) * 4096];
    float mv = 1.f / (1.f + expf(-mz));
    float py  = (float)(y + (k / 3) - 1) + oy;
    float pxf = (float)(p + (k % 3) - 1) + ox;
    float y0f = floorf(py), x0f = floorf(pxf);
    int y0 = (int)y0f, x0 = (int)x0f;
    float ly = py - y0f, lx = pxf - x0f;
    int y1 = y0 + 1, x1 = x0 + 1;
    bool vy0 = (y0 >= 0) && (y0 < 64), vy1 = (y1 >= 0) && (y1 < 64);
    bool vx0 = (x0 >= 0) && (x0 < 64), vx1 = (x1 >= 0) && (x1 < 64);
    int cy0 = min(max(y0, 0), 63), cy1 = min(max(y1, 0), 63);
    int cx0 = min(max(x0, 0), 63), cx1 = min(max(x1, 0), 63);
    f32x4 sv;
    sv.x = (vy0 && vx0) ? (1.f - ly) * (1.f - lx) * mv : 0.f;
    sv.y = (vy0 && vx1) ? (1.f - ly) * lx * mv : 0.f;
    sv.z = (vy1 && vx0) ? ly * (1.f - lx) * mv : 0.f;
    sv.w = (vy1 && vx1) ? ly * lx * mv : 0.f;
    i32x4 lv;
    lv.x = (cy0 * 64 + cx0) * 256;
    lv.y = (cy0 * 64 + cx1) * 256;
    lv.z = (cy1 * 64 + cx0) * 256;
    lv.w = (cy1 * 64 + cx1) * 256;
    swgtv[i] = sv;
    slinv[i] = lv;
  }

  f32x4 acc[4][2];
  #pragma unroll
  for (int fm = 0; fm < 4; ++fm)
    #pragma unroll
    for (int fn = 0; fn < 2; ++fn)
      acc[fm][fn] = (f32x4){0.f, 0.f, 0.f, 0.f};

  __syncthreads();                        // tables visible

  int ch0 = l15 * 8;
  // prologue: gather tap gk=0 (g=0) -> atile[0]
  {
    const __bf16* xg = xTb + ch0;
    #pragma unroll
    for (int j = 0; j < 2; ++j) {
      int p = wv * 8 + j * 4 + quad;
      f32x4 sv = swgtv[p];
      i32x4 lv = slinv[p];
      bf16x8 c0 = *(const bf16x8*)(xg + lv.x);
      bf16x8 c1 = *(const bf16x8*)(xg + lv.y);
      bf16x8 c2 = *(const bf16x8*)(xg + lv.z);
      bf16x8 c3 = *(const bf16x8*)(xg + lv.w);
      bf16x8 o;
      #pragma unroll
      for (int e = 0; e < 8; ++e)
        o[e] = (__bf16)(sv.x * (float)c0[e] + sv.y * (float)c1[e]
                      + sv.z * (float)c2[e] + sv.w * (float)c3[e]);
      *(bf16x8*)&atile[0][ATIDX(p, l15)] = o;
    }
  }
  // prologue: B-frags for gk=0
  bf16x8 Bf[8];
  {
    const __bf16* bb = wFragD + ((size_t)wv * 2) * 512 + lane * 8;
    #pragma unroll
    for (int kc = 0; kc < 4; ++kc) {
      Bf[kc * 2]     = *(const bf16x8*)(bb + (size_t)kc * 16 * 512);
      Bf[kc * 2 + 1] = *(const bf16x8*)(bb + (size_t)kc * 16 * 512 + 512);
    }
  }

  for (int gk = 0; gk < 18; ++gk) {
    __syncthreads();                      // atile[gk&1] ready
    // issue gather loads for tap gk+1
    bf16x8 cr[2][4];
    f32x4 sv[2];
    int pj[2];
    if (gk < 17) {
      int gn = gk + 1;
      const __bf16* xg = xTb + (gn / 9) * 128 + ch0;
      #pragma unroll
      for (int j = 0; j < 2; ++j) {
        int p = wv * 8 + j * 4 + quad;
        pj[j] = p;
        sv[j] = swgtv[gn * 64 + p];
        i32x4 lv = slinv[gn * 64 + p];
        cr[j][0] = *(const bf16x8*)(xg + lv.x);
        cr[j][1] = *(const bf16x8*)(xg + lv.y);
        cr[j][2] = *(const bf16x8*)(xg + lv.z);
        cr[j][3] = *(const bf16x8*)(xg + lv.w);
      }
    }
    // MFMA on atile[gk&1] with pre-loaded Bf (no post-barrier B wait)
    const __bf16* at = atile[gk & 1];
    #pragma unroll
    for (int kc = 0; kc < 4; ++kc) {
      #pragma unroll
      for (int fm = 0; fm < 4; ++fm) {
        bf16x8 a = *(const bf16x8*)&at[ATIDX(fm * 16 + l15, kc * 4 + quad)];
        acc[fm][0] = MFMA16(a, Bf[kc * 2],     acc[fm][0]);
        acc[fm][1] = MFMA16(a, Bf[kc * 2 + 1], acc[fm][1]);
      }
    }
    // combine + write tap gk+1 into the other buffer
    if (gk < 17) {
      __bf16* dst = atile[(gk + 1) & 1];
      #pragma unroll
      for (int j = 0; j < 2; ++j) {
        bf16x8 o;
        #pragma unroll
        for (int e = 0; e < 8; ++e)
          o[e] = (__bf16)(sv[j].x * (float)cr[j][0][e] + sv[j].y * (float)cr[j][1][e]
                        + sv[j].z * (float)cr[j][2][e] + sv[j].w * (float)cr[j][3][e]);
        *(bf16x8*)&dst[ATIDX(pj[j], l15)] = o;
      }
      // prefetch B-frags for gk+1 (in flight across the barrier; the barrier's
      // vmcnt drain is where waves wait anyway, so MFMA starts stall-free)
      const __bf16* bb = wFragD + ((size_t)((gk + 1) * 4) * 16 + wv * 2) * 512 + lane * 8;
      #pragma unroll
      for (int kc = 0; kc < 4; ++kc) {
        Bf[kc * 2]     = *(const bf16x8*)(bb + (size_t)kc * 16 * 512);
        Bf[kc * 2 + 1] = *(const bf16x8*)(bb + (size_t)kc * 16 * 512 + 512);
      }
    }
  }

  #pragma unroll
  for (int fm = 0; fm < 4; ++fm) {
    #pragma unroll
    for (int fn = 0; fn < 2; ++fn) {
      int oc = wv * 32 + fn * 16 + l15;
      float s = sc[oc], h = sh[oc];
      f32x4 v = acc[fm][fn];
      f32x4 r = {fmaxf(v.x * s + h, 0.f), fmaxf(v.y * s + h, 0.f),
                 fmaxf(v.z * s + h, 0.f), fmaxf(v.w * s + h, 0.f)};
      int pxs = fm * 16 + quad * 4;
      *(f32x4*)(out + (((size_t)b * 256 + oc) * 64 + y) * 64 + pxs) = r;
    }
  }
}

// ---------------------------------------------------------------------------
extern "C" void kernel_launch(void* const* d_in, const int* in_sizes, int n_in,
                              void* d_out, int out_size, void* d_ws, size_t ws_size,
                              hipStream_t stream) {
  const float* x     = (const float*)d_in[0];
  const float* w_off = (const float*)d_in[1];
  const float* b_off = (const float*)d_in[2];
  const float* w     = (const float*)d_in[3];
  const float* bconv = (const float*)d_in[4];
  const float* gamma = (const float*)d_in[5];
  const float* beta  = (const float*)d_in[6];
  const float* rmean = (const float*)d_in[7];
  const float* rvar  = (const float*)d_in[8];
  float* out = (float*)d_out;

  // ws layout (BYTE offsets):
  // om     f32 [884736]    @ 0           size 3,538,944
  // xT     bf16[4194304]   @ 3,538,944   size 8,388,608
  // wFragD bf16[589824]    @ 11,927,552  size 1,179,648
  // wFragO bf16[147456]    @ 13,107,200  size   294,912
  // sc     f32 [256]       @ 13,402,112
  // sh     f32 [256]       @ 13,403,136
  float*  om     = (float*)d_ws;
  __bf16* xT     = (__bf16*)((char*)d_ws + 3538944);
  __bf16* wFragD = (__bf16*)((char*)d_ws + 11927552);
  __bf16* wFragO = (__bf16*)((char*)d_ws + 13107200);
  float*  sc     = (float*)((char*)d_ws + 13402112);
  float*  sh     = (float*)((char*)d_ws + 13403136);

  xpose_kernel<<<4 * 64 * 4, 256, 0, stream>>>(x, xT);
  prep_kernel<<<2880, 256, 0, stream>>>(w, w_off, bconv, gamma, beta, rmean, rvar,
                                        wFragD, wFragO, sc, sh);
  offconv_kernel<<<4 * 64, 512, 0, stream>>>(xT, wFragO, b_off, om);
  dconv_kernel<<<4 * 64, 512, 0, stream>>>(xT, om, wFragD, sc, sh, out);
}

// Round 6
// 131.458 us; speedup vs baseline: 8.3962x; 1.0510x over previous
//
#include <hip/hip_runtime.h>
#include <math.h>

typedef __bf16 bf16x8 __attribute__((ext_vector_type(8)));
typedef float  f32x4  __attribute__((ext_vector_type(4)));
typedef int    i32x4  __attribute__((ext_vector_type(4)));

#define MFMA16(a, b, c) __builtin_amdgcn_mfma_f32_16x16x32_bf16((a), (b), (c), 0, 0, 0)

// A-tile: row stride 128, 16B chunks XOR-swizzled by row (kills the 4-stride
// bank pattern seen in r4: 2.36M SQ_LDS_BANK_CONFLICT).
#define ATIDX(r, c) ((r) * 128 + (((c) ^ ((r) & 7)) * 8))

// ---------------------------------------------------------------------------
// setup: merged xpose + prep (one launch).
//   blocks [0,1024):  x NCHW fp32 -> xT NHWC bf16   (per (b,y,cc))
//   blocks [1024,3904): weights -> MFMA B-fragment order + BN fold
// ---------------------------------------------------------------------------
__global__ __launch_bounds__(256) void setup_kernel(
    const float* __restrict__ x, const float* __restrict__ w,
    const float* __restrict__ w_off, const float* __restrict__ bconv,
    const float* __restrict__ gamma, const float* __restrict__ beta,
    const float* __restrict__ mean, const float* __restrict__ var,
    __bf16* __restrict__ xT, __bf16* __restrict__ wFragD,
    __bf16* __restrict__ wFragO, float* __restrict__ sc,
    float* __restrict__ sh) {
  int t = threadIdx.x;
  if (blockIdx.x < 1024) {
    __shared__ float xs[64][65];
    int b = blockIdx.x >> 8, y = (blockIdx.x >> 2) & 63, cc = blockIdx.x & 3;
    for (int i = t; i < 4096; i += 256) {
      int cl = i >> 6, xc = i & 63;
      xs[cl][xc] = x[(((size_t)b * 256 + cc * 64 + cl) * 64 + y) * 64 + xc];
    }
    __syncthreads();
    for (int i = t; i < 4096; i += 256) {
      int xc = i >> 6, cl = i & 63;
      xT[(((size_t)b * 64 + y) * 64 + xc) * 256 + cc * 64 + cl] = (__bf16)xs[cl][xc];
    }
    return;
  }
  int i = (blockIdx.x - 1024) * 256 + t;
  if (i < 589824) {
    int j = i & 7, lane = (i >> 3) & 63, ocb = (i >> 9) & 15;
    int kc = (i >> 13) & 3, gk = i >> 15;
    int klocal = (lane >> 4) * 8 + j;
    int oc = ocb * 16 + (lane & 15);
    int c = kc * 32 + klocal;
    int g = gk / 9, ktap = gk % 9;
    wFragD[i] = (__bf16)w[((size_t)oc * 256 + g * 128 + c) * 9 + ktap];
  } else {
    int i2 = i - 589824;
    int j = i2 & 7, lane = (i2 >> 3) & 63, ocb = (i2 >> 9) & 3;
    int kc = (i2 >> 11) & 7, tap = i2 >> 14;
    int klocal = (lane >> 4) * 8 + j;
    int oc = ocb * 16 + (lane & 15);
    int ci = kc * 32 + klocal;
    wFragO[i2] = (oc < 54) ? (__bf16)w_off[((size_t)oc * 256 + ci) * 9 + tap]
                           : (__bf16)0.f;
  }
  if (i < 256) {
    float s = gamma[i] * rsqrtf(var[i] + 1e-5f);
    sc[i] = s;
    sh[i] = (bconv[i] - mean[i]) * s + beta[i];
  }
}

// ---------------------------------------------------------------------------
// fused kernel: per (b,y) row block, 512 thr / 8 waves.
//   A: stage 3 padded rows -> LDS; 9-tap MFMA offset-conv -> omrow (LDS)
//   B: bilinear tables from omrow
//   C: 18-tap deformable GEMM (r5 pipeline) + BN + ReLU
// LDS union: rowbuf (phase A, 99 KB) overlaid with tables+atile (phase C,
// 68 KB); omrow (13.5 KB) persistent across A->B. Peak ~115 KB -> 1 block/CU.
// ---------------------------------------------------------------------------
struct PhaseC {
  f32x4 swgtv[18 * 64];
  i32x4 slinv[18 * 64];
  __bf16 atile[2][64 * 128];
};
union FusedLDS {
  __bf16 rowbuf[3 * 66 * 256];
  PhaseC c;
};

__global__ __launch_bounds__(512) void fused_kernel(
    const __bf16* __restrict__ xT, const __bf16* __restrict__ wFragD,
    const __bf16* __restrict__ wFragO, const float* __restrict__ b_off,
    const float* __restrict__ sc, const float* __restrict__ sh,
    float* __restrict__ out) {
  __shared__ __attribute__((aligned(16))) FusedLDS U;
  __shared__ float omrow[54 * 64];
  int t = threadIdx.x;
  int b = blockIdx.x >> 6, y = blockIdx.x & 63;
  int lane = t & 63, wv = t >> 6;
  int l15 = lane & 15, quad = lane >> 4;
  const __bf16* xTb = xT + (size_t)b * 64 * 64 * 256;
  bf16x8 z8;
  #pragma unroll
  for (int e = 0; e < 8; ++e) z8[e] = (__bf16)0.f;

  // ---- phase A: stage rowbuf[dy][px66][ch] (px66 = x+1; cols 0,65 zero) ----
  for (int i = t; i < 3 * 66 * 32; i += 512) {
    int c = i & 31, px66 = (i >> 5) % 66, dy = i / 2112;
    int y2 = y + dy - 1, x2 = px66 - 1;
    bf16x8 v = z8;
    if (y2 >= 0 && y2 < 64 && x2 >= 0 && x2 < 64)
      v = *(const bf16x8*)(xTb + ((size_t)y2 * 64 + x2) * 256 + c * 8);
    *(bf16x8*)&U.rowbuf[dy * 16896 + px66 * 256 + ((c ^ (px66 & 7)) * 8)] = v;
  }
  __syncthreads();

  // offset-conv: 9 taps pure MFMA from rowbuf (shifted window, no barriers)
  {
    int mh = wv & 1, ocq = wv >> 1;
    f32x4 acc0 = {0.f, 0.f, 0.f, 0.f};
    f32x4 acc1 = {0.f, 0.f, 0.f, 0.f};
    for (int tap = 0; tap < 9; ++tap) {
      int dy = tap / 3, dxs = tap % 3;
      const __bf16* bb = wFragO + ((size_t)(tap * 8) * 4 + ocq) * 512 + lane * 8;
      bf16x8 Bf[8];
      #pragma unroll
      for (int kc = 0; kc < 8; ++kc)
        Bf[kc] = *(const bf16x8*)(bb + (size_t)kc * 4 * 512);
      int p0 = mh * 32 + l15 + dxs, p1 = p0 + 16;
      const __bf16* rb = U.rowbuf + dy * 16896;
      #pragma unroll
      for (int kc = 0; kc < 8; ++kc) {
        int c = kc * 4 + quad;
        bf16x8 a0 = *(const bf16x8*)&rb[p0 * 256 + ((c ^ (p0 & 7)) * 8)];
        bf16x8 a1 = *(const bf16x8*)&rb[p1 * 256 + ((c ^ (p1 & 7)) * 8)];
        acc0 = MFMA16(a0, Bf[kc], acc0);
        acc1 = MFMA16(a1, Bf[kc], acc1);
      }
    }
    int oc = ocq * 16 + l15;
    if (oc < 54) {
      float bo = b_off[oc];
      #pragma unroll
      for (int fm = 0; fm < 2; ++fm) {
        f32x4 v = fm ? acc1 : acc0;
        f32x4 r = {v.x + bo, v.y + bo, v.z + bo, v.w + bo};
        int pxs = mh * 32 + fm * 16 + quad * 4;
        *(f32x4*)&omrow[oc * 64 + pxs] = r;
      }
    }
  }
  __syncthreads();                        // omrow ready; rowbuf now dead

  // ---- phase B: bilinear corner tables from omrow ----
  for (int i = t; i < 18 * 64; i += 512) {
    int gk = i >> 6, p = i & 63;
    int k = gk % 9;
    float oy = omrow[gk * 64 + p];
    float ox = omrow[(18 + gk) * 64 + p];
    float mz = omrow[(36 + gk) * 64 + p];
    float mv = 1.f / (1.f + expf(-mz));
    float py  = (float)(y + (k / 3) - 1) + oy;
    float pxf = (float)(p + (k % 3) - 1) + ox;
    float y0f = floorf(py), x0f = floorf(pxf);
    int y0 = (int)y0f, x0 = (int)x0f;
    float ly = py - y0f, lx = pxf - x0f;
    int y1 = y0 + 1, x1 = x0 + 1;
    bool vy0 = (y0 >= 0) && (y0 < 64), vy1 = (y1 >= 0) && (y1 < 64);
    bool vx0 = (x0 >= 0) && (x0 < 64), vx1 = (x1 >= 0) && (x1 < 64);
    int cy0 = min(max(y0, 0), 63), cy1 = min(max(y1, 0), 63);
    int cx0 = min(max(x0, 0), 63), cx1 = min(max(x1, 0), 63);
    f32x4 sv;
    sv.x = (vy0 && vx0) ? (1.f - ly) * (1.f - lx) * mv : 0.f;
    sv.y = (vy0 && vx1) ? (1.f - ly) * lx * mv : 0.f;
    sv.z = (vy1 && vx0) ? ly * (1.f - lx) * mv : 0.f;
    sv.w = (vy1 && vx1) ? ly * lx * mv : 0.f;
    i32x4 lv;
    lv.x = (cy0 * 64 + cx0) * 256;
    lv.y = (cy0 * 64 + cx1) * 256;
    lv.z = (cy1 * 64 + cx0) * 256;
    lv.w = (cy1 * 64 + cx1) * 256;
    U.c.swgtv[i] = sv;
    U.c.slinv[i] = lv;
  }

  f32x4 acc[4][2];
  #pragma unroll
  for (int fm = 0; fm < 4; ++fm)
    #pragma unroll
    for (int fn = 0; fn < 2; ++fn)
      acc[fm][fn] = (f32x4){0.f, 0.f, 0.f, 0.f};

  __syncthreads();                        // tables visible

  // ---- phase C: deformable GEMM (r5 pipeline, unchanged) ----
  int ch0 = l15 * 8;
  {
    const __bf16* xg = xTb + ch0;
    #pragma unroll
    for (int j = 0; j < 2; ++j) {
      int p = wv * 8 + j * 4 + quad;
      f32x4 sv = U.c.swgtv[p];
      i32x4 lv = U.c.slinv[p];
      bf16x8 c0 = *(const bf16x8*)(xg + lv.x);
      bf16x8 c1 = *(const bf16x8*)(xg + lv.y);
      bf16x8 c2 = *(const bf16x8*)(xg + lv.z);
      bf16x8 c3 = *(const bf16x8*)(xg + lv.w);
      bf16x8 o;
      #pragma unroll
      for (int e = 0; e < 8; ++e)
        o[e] = (__bf16)(sv.x * (float)c0[e] + sv.y * (float)c1[e]
                      + sv.z * (float)c2[e] + sv.w * (float)c3[e]);
      *(bf16x8*)&U.c.atile[0][ATIDX(p, l15)] = o;
    }
  }
  bf16x8 Bf[8];
  {
    const __bf16* bb = wFragD + ((size_t)wv * 2) * 512 + lane * 8;
    #pragma unroll
    for (int kc = 0; kc < 4; ++kc) {
      Bf[kc * 2]     = *(const bf16x8*)(bb + (size_t)kc * 16 * 512);
      Bf[kc * 2 + 1] = *(const bf16x8*)(bb + (size_t)kc * 16 * 512 + 512);
    }
  }

  for (int gk = 0; gk < 18; ++gk) {
    __syncthreads();                      // atile[gk&1] ready
    bf16x8 cr[2][4];
    f32x4 sv[2];
    int pj[2];
    if (gk < 17) {
      int gn = gk + 1;
      const __bf16* xg = xTb + (gn / 9) * 128 + ch0;
      #pragma unroll
      for (int j = 0; j < 2; ++j) {
        int p = wv * 8 + j * 4 + quad;
        pj[j] = p;
        sv[j] = U.c.swgtv[gn * 64 + p];
        i32x4 lv = U.c.slinv[gn * 64 + p];
        cr[j][0] = *(const bf16x8*)(xg + lv.x);
        cr[j][1] = *(const bf16x8*)(xg + lv.y);
        cr[j][2] = *(const bf16x8*)(xg + lv.z);
        cr[j][3] = *(const bf16x8*)(xg + lv.w);
      }
    }
    const __bf16* at = U.c.atile[gk & 1];
    #pragma unroll
    for (int kc = 0; kc < 4; ++kc) {
      #pragma unroll
      for (int fm = 0; fm < 4; ++fm) {
        bf16x8 a = *(const bf16x8*)&at[ATIDX(fm * 16 + l15, kc * 4 + quad)];
        acc[fm][0] = MFMA16(a, Bf[kc * 2],     acc[fm][0]);
        acc[fm][1] = MFMA16(a, Bf[kc * 2 + 1], acc[fm][1]);
      }
    }
    if (gk < 17) {
      __bf16* dst = U.c.atile[(gk + 1) & 1];
      #pragma unroll
      for (int j = 0; j < 2; ++j) {
        bf16x8 o;
        #pragma unroll
        for (int e = 0; e < 8; ++e)
          o[e] = (__bf16)(sv[j].x * (float)cr[j][0][e] + sv[j].y * (float)cr[j][1][e]
                        + sv[j].z * (float)cr[j][2][e] + sv[j].w * (float)cr[j][3][e]);
        *(bf16x8*)&dst[ATIDX(pj[j], l15)] = o;
      }
      const __bf16* bb = wFragD + ((size_t)((gk + 1) * 4) * 16 + wv * 2) * 512 + lane * 8;
      #pragma unroll
      for (int kc = 0; kc < 4; ++kc) {
        Bf[kc * 2]     = *(const bf16x8*)(bb + (size_t)kc * 16 * 512);
        Bf[kc * 2 + 1] = *(const bf16x8*)(bb + (size_t)kc * 16 * 512 + 512);
      }
    }
  }

  #pragma unroll
  for (int fm = 0; fm < 4; ++fm) {
    #pragma unroll
    for (int fn = 0; fn < 2; ++fn) {
      int oc = wv * 32 + fn * 16 + l15;
      float s = sc[oc], h = sh[oc];
      f32x4 v = acc[fm][fn];
      f32x4 r = {fmaxf(v.x * s + h, 0.f), fmaxf(v.y * s + h, 0.f),
                 fmaxf(v.z * s + h, 0.f), fmaxf(v.w * s + h, 0.f)};
      int pxs = fm * 16 + quad * 4;
      *(f32x4*)(out + (((size_t)b * 256 + oc) * 64 + y) * 64 + pxs) = r;
    }
  }
}

// ---------------------------------------------------------------------------
extern "C" void kernel_launch(void* const* d_in, const int* in_sizes, int n_in,
                              void* d_out, int out_size, void* d_ws, size_t ws_size,
                              hipStream_t stream) {
  const float* x     = (const float*)d_in[0];
  const float* w_off = (const float*)d_in[1];
  const float* b_off = (const float*)d_in[2];
  const float* w     = (const float*)d_in[3];
  const float* bconv = (const float*)d_in[4];
  const float* gamma = (const float*)d_in[5];
  const float* beta  = (const float*)d_in[6];
  const float* rmean = (const float*)d_in[7];
  const float* rvar  = (const float*)d_in[8];
  float* out = (float*)d_out;

  // ws layout (BYTE offsets):
  // xT     bf16[4194304]   @ 0          size 8,388,608
  // wFragD bf16[589824]    @ 8,388,608  size 1,179,648
  // wFragO bf16[147456]    @ 9,568,256  size   294,912
  // sc     f32 [256]       @ 9,863,168
  // sh     f32 [256]       @ 9,864,192
  __bf16* xT     = (__bf16*)d_ws;
  __bf16* wFragD = (__bf16*)((char*)d_ws + 8388608);
  __bf16* wFragO = (__bf16*)((char*)d_ws + 9568256);
  float*  sc     = (float*)((char*)d_ws + 9863168);
  float*  sh     = (float*)((char*)d_ws + 9864192);

  setup_kernel<<<1024 + 2880, 256, 0, stream>>>(
      x, w, w_off, bconv, gamma, beta, rmean, rvar, xT, wFragD, wFragO, sc, sh);
  fused_kernel<<<4 * 64, 512, 0, stream>>>(xT, wFragD, wFragO, b_off, sc, sh, out);
}

// Round 7
// 131.044 us; speedup vs baseline: 8.4227x; 1.0032x over previous
//
#include <hip/hip_runtime.h>
#include <math.h>

typedef __bf16 bf16x8 __attribute__((ext_vector_type(8)));
typedef float  f32x4  __attribute__((ext_vector_type(4)));
typedef int    i32x4  __attribute__((ext_vector_type(4)));

#define MFMA16(a, b, c) __builtin_amdgcn_mfma_f32_16x16x32_bf16((a), (b), (c), 0, 0, 0)

// A-tile: row stride 128 elements, 16B chunks XOR-swizzled by row (16-row
// reads hit each bank-pair 2-way = free per m136).
#define ATIDX(r, c) ((r) * 128 + (((c) ^ ((r) & 7)) * 8))

// ---------------------------------------------------------------------------
// setup: merged xpose + prep.
// ---------------------------------------------------------------------------
__global__ __launch_bounds__(256) void setup_kernel(
    const float* __restrict__ x, const float* __restrict__ w,
    const float* __restrict__ w_off, const float* __restrict__ bconv,
    const float* __restrict__ gamma, const float* __restrict__ beta,
    const float* __restrict__ mean, const float* __restrict__ var,
    __bf16* __restrict__ xT, __bf16* __restrict__ wFragD,
    __bf16* __restrict__ wFragO, float* __restrict__ sc,
    float* __restrict__ sh) {
  int t = threadIdx.x;
  if (blockIdx.x < 1024) {
    __shared__ float xs[64][65];
    int b = blockIdx.x >> 8, y = (blockIdx.x >> 2) & 63, cc = blockIdx.x & 3;
    for (int i = t; i < 4096; i += 256) {
      int cl = i >> 6, xc = i & 63;
      xs[cl][xc] = x[(((size_t)b * 256 + cc * 64 + cl) * 64 + y) * 64 + xc];
    }
    __syncthreads();
    for (int i = t; i < 4096; i += 256) {
      int xc = i >> 6, cl = i & 63;
      xT[(((size_t)b * 64 + y) * 64 + xc) * 256 + cc * 64 + cl] = (__bf16)xs[cl][xc];
    }
    return;
  }
  int i = (blockIdx.x - 1024) * 256 + t;
  if (i < 589824) {
    int j = i & 7, lane = (i >> 3) & 63, ocb = (i >> 9) & 15;
    int kc = (i >> 13) & 3, gk = i >> 15;
    int klocal = (lane >> 4) * 8 + j;
    int oc = ocb * 16 + (lane & 15);
    int c = kc * 32 + klocal;
    int g = gk / 9, ktap = gk % 9;
    wFragD[i] = (__bf16)w[((size_t)oc * 256 + g * 128 + c) * 9 + ktap];
  } else {
    int i2 = i - 589824;
    int j = i2 & 7, lane = (i2 >> 3) & 63, ocb = (i2 >> 9) & 3;
    int kc = (i2 >> 11) & 7, tap = i2 >> 14;
    int klocal = (lane >> 4) * 8 + j;
    int oc = ocb * 16 + (lane & 15);
    int ci = kc * 32 + klocal;
    wFragO[i2] = (oc < 54) ? (__bf16)w_off[((size_t)oc * 256 + ci) * 9 + tap]
                           : (__bf16)0.f;
  }
  if (i < 256) {
    float s = gamma[i] * rsqrtf(var[i] + 1e-5f);
    sc[i] = s;
    sh[i] = (bconv[i] - mean[i]) * s + beta[i];
  }
}

// ---------------------------------------------------------------------------
// fused kernel. Phase C now runs 2 taps per barrier interval with a
// register-pinned pipeline (sched_barrier fences; B-loads issued before
// gathers so monotone vmcnt drains never stall MFMA on gather completion).
// ---------------------------------------------------------------------------
struct PhaseC {
  f32x4 swgtv[18 * 64];
  i32x4 slinv[18 * 64];
  __bf16 atile[2][2][64 * 128];   // [buf][tap-in-pair][...]
};
union FusedLDS {
  __bf16 rowbuf[3 * 66 * 256];
  PhaseC c;
};

__global__ __launch_bounds__(512) void fused_kernel(
    const __bf16* __restrict__ xT, const __bf16* __restrict__ wFragD,
    const __bf16* __restrict__ wFragO, const float* __restrict__ b_off,
    const float* __restrict__ sc, const float* __restrict__ sh,
    float* __restrict__ out) {
  __shared__ __attribute__((aligned(16))) FusedLDS U;
  __shared__ float omrow[54 * 64];
  int t = threadIdx.x;
  int b = blockIdx.x >> 6, y = blockIdx.x & 63;
  int lane = t & 63, wv = t >> 6;
  int l15 = lane & 15, quad = lane >> 4;
  const __bf16* xTb = xT + (size_t)b * 64 * 64 * 256;
  bf16x8 z8;
  #pragma unroll
  for (int e = 0; e < 8; ++e) z8[e] = (__bf16)0.f;

  // ---- phase A: stage rowbuf[dy][px66][ch] ----
  for (int i = t; i < 3 * 66 * 32; i += 512) {
    int c = i & 31, px66 = (i >> 5) % 66, dy = i / 2112;
    int y2 = y + dy - 1, x2 = px66 - 1;
    bf16x8 v = z8;
    if (y2 >= 0 && y2 < 64 && x2 >= 0 && x2 < 64)
      v = *(const bf16x8*)(xTb + ((size_t)y2 * 64 + x2) * 256 + c * 8);
    *(bf16x8*)&U.rowbuf[dy * 16896 + px66 * 256 + ((c ^ (px66 & 7)) * 8)] = v;
  }
  __syncthreads();

  // offset-conv: 9 taps pure MFMA from rowbuf
  {
    int mh = wv & 1, ocq = wv >> 1;
    f32x4 acc0 = {0.f, 0.f, 0.f, 0.f};
    f32x4 acc1 = {0.f, 0.f, 0.f, 0.f};
    for (int tap = 0; tap < 9; ++tap) {
      int dy = tap / 3, dxs = tap % 3;
      const __bf16* bb = wFragO + ((size_t)(tap * 8) * 4 + ocq) * 512 + lane * 8;
      bf16x8 Bf[8];
      #pragma unroll
      for (int kc = 0; kc < 8; ++kc)
        Bf[kc] = *(const bf16x8*)(bb + (size_t)kc * 4 * 512);
      int p0 = mh * 32 + l15 + dxs, p1 = p0 + 16;
      const __bf16* rb = U.rowbuf + dy * 16896;
      #pragma unroll
      for (int kc = 0; kc < 8; ++kc) {
        int c = kc * 4 + quad;
        bf16x8 a0 = *(const bf16x8*)&rb[p0 * 256 + ((c ^ (p0 & 7)) * 8)];
        bf16x8 a1 = *(const bf16x8*)&rb[p1 * 256 + ((c ^ (p1 & 7)) * 8)];
        acc0 = MFMA16(a0, Bf[kc], acc0);
        acc1 = MFMA16(a1, Bf[kc], acc1);
      }
    }
    int oc = ocq * 16 + l15;
    if (oc < 54) {
      float bo = b_off[oc];
      #pragma unroll
      for (int fm = 0; fm < 2; ++fm) {
        f32x4 v = fm ? acc1 : acc0;
        f32x4 r = {v.x + bo, v.y + bo, v.z + bo, v.w + bo};
        int pxs = mh * 32 + fm * 16 + quad * 4;
        *(f32x4*)&omrow[oc * 64 + pxs] = r;
      }
    }
  }
  __syncthreads();                        // omrow ready; rowbuf dead

  // ---- phase B: bilinear corner tables from omrow ----
  for (int i = t; i < 18 * 64; i += 512) {
    int gk = i >> 6, p = i & 63;
    int k = gk % 9;
    float oy = omrow[gk * 64 + p];
    float ox = omrow[(18 + gk) * 64 + p];
    float mz = omrow[(36 + gk) * 64 + p];
    float mv = 1.f / (1.f + expf(-mz));
    float py  = (float)(y + (k / 3) - 1) + oy;
    float pxf = (float)(p + (k % 3) - 1) + ox;
    float y0f = floorf(py), x0f = floorf(pxf);
    int y0 = (int)y0f, x0 = (int)x0f;
    float ly = py - y0f, lx = pxf - x0f;
    int y1 = y0 + 1, x1 = x0 + 1;
    bool vy0 = (y0 >= 0) && (y0 < 64), vy1 = (y1 >= 0) && (y1 < 64);
    bool vx0 = (x0 >= 0) && (x0 < 64), vx1 = (x1 >= 0) && (x1 < 64);
    int cy0 = min(max(y0, 0), 63), cy1 = min(max(y1, 0), 63);
    int cx0 = min(max(x0, 0), 63), cx1 = min(max(x1, 0), 63);
    f32x4 sv;
    sv.x = (vy0 && vx0) ? (1.f - ly) * (1.f - lx) * mv : 0.f;
    sv.y = (vy0 && vx1) ? (1.f - ly) * lx * mv : 0.f;
    sv.z = (vy1 && vx0) ? ly * (1.f - lx) * mv : 0.f;
    sv.w = (vy1 && vx1) ? ly * lx * mv : 0.f;
    i32x4 lv;
    lv.x = (cy0 * 64 + cx0) * 256;
    lv.y = (cy0 * 64 + cx1) * 256;
    lv.z = (cy1 * 64 + cx0) * 256;
    lv.w = (cy1 * 64 + cx1) * 256;
    U.c.swgtv[i] = sv;
    U.c.slinv[i] = lv;
  }

  f32x4 acc[4][2];
  #pragma unroll
  for (int fm = 0; fm < 4; ++fm)
    #pragma unroll
    for (int fn = 0; fn < 2; ++fn)
      acc[fm][fn] = (f32x4){0.f, 0.f, 0.f, 0.f};

  __syncthreads();                        // tables visible; rowbuf region free

  int ch0 = l15 * 8;
  // prologue: gather taps 0 and 1 directly into atile[0][0/1]
  #pragma unroll
  for (int t2 = 0; t2 < 2; ++t2) {
    const __bf16* xg = xTb + ch0;         // taps 0,1 are group 0
    #pragma unroll
    for (int j = 0; j < 2; ++j) {
      int p = wv * 8 + j * 4 + quad;
      f32x4 sv = U.c.swgtv[t2 * 64 + p];
      i32x4 lv = U.c.slinv[t2 * 64 + p];
      bf16x8 c0 = *(const bf16x8*)(xg + lv.x);
      bf16x8 c1 = *(const bf16x8*)(xg + lv.y);
      bf16x8 c2 = *(const bf16x8*)(xg + lv.z);
      bf16x8 c3 = *(const bf16x8*)(xg + lv.w);
      bf16x8 o;
      #pragma unroll
      for (int e = 0; e < 8; ++e)
        o[e] = (__bf16)(sv.x * (float)c0[e] + sv.y * (float)c1[e]
                      + sv.z * (float)c2[e] + sv.w * (float)c3[e]);
      *(bf16x8*)&U.c.atile[0][t2][ATIDX(p, l15)] = o;
    }
  }

  // ---- phase C main loop: 9 intervals of 2 taps ----
  for (int iv = 0; iv < 9; ++iv) {
    __syncthreads();                      // atile[iv&1][*] ready
    // B-frags for taps 2iv, 2iv+1 — issued FIRST (oldest in vmcnt queue)
    bf16x8 Bf0[8], Bf1[8];
    {
      const __bf16* bb0 = wFragD + ((size_t)(2 * iv) * 4 * 16 + wv * 2) * 512 + lane * 8;
      const __bf16* bb1 = bb0 + (size_t)4 * 16 * 512;
      #pragma unroll
      for (int kc = 0; kc < 4; ++kc) {
        Bf0[kc * 2]     = *(const bf16x8*)(bb0 + (size_t)kc * 16 * 512);
        Bf0[kc * 2 + 1] = *(const bf16x8*)(bb0 + (size_t)kc * 16 * 512 + 512);
      }
      #pragma unroll
      for (int kc = 0; kc < 4; ++kc) {
        Bf1[kc * 2]     = *(const bf16x8*)(bb1 + (size_t)kc * 16 * 512);
        Bf1[kc * 2 + 1] = *(const bf16x8*)(bb1 + (size_t)kc * 16 * 512 + 512);
      }
    }
    // gathers for taps 2iv+2, 2iv+3 (in flight across the MFMA section)
    bf16x8 cr[2][2][4];
    f32x4 sv[2][2];
    if (iv < 8) {
      #pragma unroll
      for (int t2 = 0; t2 < 2; ++t2) {
        int gn = 2 * iv + 2 + t2;
        const __bf16* xg = xTb + (gn / 9) * 128 + ch0;
        #pragma unroll
        for (int j = 0; j < 2; ++j) {
          int p = wv * 8 + j * 4 + quad;
          sv[t2][j] = U.c.swgtv[gn * 64 + p];
          i32x4 lv = U.c.slinv[gn * 64 + p];
          cr[t2][j][0] = *(const bf16x8*)(xg + lv.x);
          cr[t2][j][1] = *(const bf16x8*)(xg + lv.y);
          cr[t2][j][2] = *(const bf16x8*)(xg + lv.z);
          cr[t2][j][3] = *(const bf16x8*)(xg + lv.w);
        }
      }
    }
    __builtin_amdgcn_sched_barrier(0);    // pin: loads above, MFMA below
    {
      const __bf16* at0 = U.c.atile[iv & 1][0];
      #pragma unroll
      for (int kc = 0; kc < 4; ++kc) {
        #pragma unroll
        for (int fm = 0; fm < 4; ++fm) {
          bf16x8 a = *(const bf16x8*)&at0[ATIDX(fm * 16 + l15, kc * 4 + quad)];
          acc[fm][0] = MFMA16(a, Bf0[kc * 2],     acc[fm][0]);
          acc[fm][1] = MFMA16(a, Bf0[kc * 2 + 1], acc[fm][1]);
        }
      }
      const __bf16* at1 = U.c.atile[iv & 1][1];
      #pragma unroll
      for (int kc = 0; kc < 4; ++kc) {
        #pragma unroll
        for (int fm = 0; fm < 4; ++fm) {
          bf16x8 a = *(const bf16x8*)&at1[ATIDX(fm * 16 + l15, kc * 4 + quad)];
          acc[fm][0] = MFMA16(a, Bf1[kc * 2],     acc[fm][0]);
          acc[fm][1] = MFMA16(a, Bf1[kc * 2 + 1], acc[fm][1]);
        }
      }
    }
    __builtin_amdgcn_sched_barrier(0);    // keep convert/writes below MFMA
    if (iv < 8) {
      #pragma unroll
      for (int t2 = 0; t2 < 2; ++t2) {
        __bf16* dst = U.c.atile[(iv + 1) & 1][t2];
        #pragma unroll
        for (int j = 0; j < 2; ++j) {
          int p = wv * 8 + j * 4 + quad;
          bf16x8 o;
          #pragma unroll
          for (int e = 0; e < 8; ++e)
            o[e] = (__bf16)(sv[t2][j].x * (float)cr[t2][j][0][e]
                          + sv[t2][j].y * (float)cr[t2][j][1][e]
                          + sv[t2][j].z * (float)cr[t2][j][2][e]
                          + sv[t2][j].w * (float)cr[t2][j][3][e]);
          *(bf16x8*)&dst[ATIDX(p, l15)] = o;
        }
      }
    }
  }

  #pragma unroll
  for (int fm = 0; fm < 4; ++fm) {
    #pragma unroll
    for (int fn = 0; fn < 2; ++fn) {
      int oc = wv * 32 + fn * 16 + l15;
      float s = sc[oc], h = sh[oc];
      f32x4 v = acc[fm][fn];
      f32x4 r = {fmaxf(v.x * s + h, 0.f), fmaxf(v.y * s + h, 0.f),
                 fmaxf(v.z * s + h, 0.f), fmaxf(v.w * s + h, 0.f)};
      int pxs = fm * 16 + quad * 4;
      *(f32x4*)(out + (((size_t)b * 256 + oc) * 64 + y) * 64 + pxs) = r;
    }
  }
}

// ---------------------------------------------------------------------------
extern "C" void kernel_launch(void* const* d_in, const int* in_sizes, int n_in,
                              void* d_out, int out_size, void* d_ws, size_t ws_size,
                              hipStream_t stream) {
  const float* x     = (const float*)d_in[0];
  const float* w_off = (const float*)d_in[1];
  const float* b_off = (const float*)d_in[2];
  const float* w     = (const float*)d_in[3];
  const float* bconv = (const float*)d_in[4];
  const float* gamma = (const float*)d_in[5];
  const float* beta  = (const float*)d_in[6];
  const float* rmean = (const float*)d_in[7];
  const float* rvar  = (const float*)d_in[8];
  float* out = (float*)d_out;

  __bf16* xT     = (__bf16*)d_ws;                          // 8,388,608 B
  __bf16* wFragD = (__bf16*)((char*)d_ws + 8388608);       // 1,179,648 B
  __bf16* wFragO = (__bf16*)((char*)d_ws + 9568256);       //   294,912 B
  float*  sc     = (float*)((char*)d_ws + 9863168);
  float*  sh     = (float*)((char*)d_ws + 9864192);

  setup_kernel<<<1024 + 2880, 256, 0, stream>>>(
      x, w, w_off, bconv, gamma, beta, rmean, rvar, xT, wFragD, wFragO, sc, sh);
  fused_kernel<<<4 * 64, 512, 0, stream>>>(xT, wFragD, wFragO, b_off, sc, sh, out);
}